// Round 5
// baseline (149.770 us; speedup 1.0000x reference)
//
#include <hip/hip_runtime.h>

// ClebschCombiningSingleUnrolled: out[mu] += mult * X1[m1] * X2[m2] over N*D points.
// M=9, K=100, P = N*D = 1048576.
//
// R5: dense-bilinear register kernel. prep folds the K sparse terms into a
// dense Cd[81 pairs][9 mu] table (729 floats, duplicates accumulated).
// Main kernel: fully static unrolled nest -- X1/X2/acc in registers,
// coefficients broadcast from a 12-VGPR lane-distributed copy of Cd via
// v_readlane with compile-time reg+lane. No LDS, no runtime addressing,
// no branches: nothing left to be latency-bound on except the streaming
// input loads (issued 18-wide up front) and the fmac stream.

#define M_CH 9
#define CSIZE 768            // 729 padded to 12*64 lanes

__global__ __launch_bounds__(64) void prep_kernel(
    const int* __restrict__ m1, const int* __restrict__ m2,
    const int* __restrict__ mu, const float* __restrict__ mult,
    int K, float* __restrict__ Cd) {
    if (threadIdx.x == 0) {
        for (int i = 0; i < CSIZE; ++i) Cd[i] = 0.f;
        for (int k = 0; k < K; ++k) {
            const int idx = (m1[k] * M_CH + m2[k]) * M_CH + mu[k];
            Cd[idx] += mult[k];
        }
    }
}

__global__ __launch_bounds__(64) void cleb_dense(
    const float* __restrict__ X1, const float* __restrict__ X2,
    const float* __restrict__ Cd, float* __restrict__ out, int P) {
    const int lane = threadIdx.x;
    const size_t base = (size_t)blockIdx.x * 256 + (size_t)lane * 4;

    // 18 independent 16B input loads issued up front
    float4 x1[M_CH], x2[M_CH];
    #pragma unroll
    for (int m = 0; m < M_CH; ++m) {
        x1[m] = *(const float4*)(X1 + (size_t)m * P + base);
        x2[m] = *(const float4*)(X2 + (size_t)m * P + base);
    }

    // lane-distributed coefficient table: tab[r] holds Cd[r*64 + lane]
    int tab[12];
    #pragma unroll
    for (int r = 0; r < 12; ++r)
        tab[r] = ((const int*)Cd)[r * 64 + lane];

    float4 acc[M_CH];
    #pragma unroll
    for (int m = 0; m < M_CH; ++m) acc[m] = make_float4(0.f, 0.f, 0.f, 0.f);

    #pragma unroll
    for (int p1 = 0; p1 < M_CH; ++p1) {
        #pragma unroll
        for (int p2 = 0; p2 < M_CH; ++p2) {
            float4 prod;
            prod.x = x1[p1].x * x2[p2].x;
            prod.y = x1[p1].y * x2[p2].y;
            prod.z = x1[p1].z * x2[p2].z;
            prod.w = x1[p1].w * x2[p2].w;
            #pragma unroll
            for (int m = 0; m < M_CH; ++m) {
                const int idx = (p1 * M_CH + p2) * M_CH + m;   // compile-time
                const float c = __int_as_float(
                    __builtin_amdgcn_readlane(tab[idx >> 6], idx & 63));
                acc[m].x = fmaf(c, prod.x, acc[m].x);
                acc[m].y = fmaf(c, prod.y, acc[m].y);
                acc[m].z = fmaf(c, prod.z, acc[m].z);
                acc[m].w = fmaf(c, prod.w, acc[m].w);
            }
        }
    }

    #pragma unroll
    for (int m = 0; m < M_CH; ++m)
        *(float4*)(out + (size_t)m * P + base) = acc[m];
}

extern "C" void kernel_launch(void* const* d_in, const int* in_sizes, int n_in,
                              void* d_out, int out_size, void* d_ws, size_t ws_size,
                              hipStream_t stream) {
    const float* X1   = (const float*)d_in[0];
    const float* X2   = (const float*)d_in[1];
    const int*   m1   = (const int*)d_in[2];
    const int*   m2   = (const int*)d_in[3];
    const int*   mu   = (const int*)d_in[4];
    const float* mult = (const float*)d_in[5];
    float* out = (float*)d_out;
    float* Cd  = (float*)d_ws;

    const int K = in_sizes[2];                 // 100
    const int P = in_sizes[0] / M_CH;          // 1048576

    prep_kernel<<<1, 64, 0, stream>>>(m1, m2, mu, mult, K, Cd);
    cleb_dense<<<P / 256, 64, 0, stream>>>(X1, X2, Cd, out, P);
}

// Round 7
// 127.216 us; speedup vs baseline: 1.1773x; 1.1773x over previous
//
#include <hip/hip_runtime.h>

// ClebschCombiningSingleUnrolled: out[mu] += mult * X1[m1] * X2[m2] over N*D points.
// M=9, K=100, P = N*D = 1048576.
//
// R7 == R6 (infra failure, never measured): dense-bilinear register kernel.
//  - prep: parallel zero + atomicAdd scatter into dense Cd[81 pairs][9 mu]
//    (R5's single-lane RMW loop was ~20-40us of alias-serialized latency).
//  - cleb: coefficients via wave-uniform scalar loads (compiler emits s_load;
//    no readlane, no VGPR table), math packed as float2 so hipcc can emit
//    v_pk_fma_f32. Fully static unroll: X1/X2/acc in registers, no LDS,
//    no runtime indexing, no branches.

#define M_CH 9
#define CSIZE 768            // 729 padded

typedef float v2f __attribute__((ext_vector_type(2)));

__global__ __launch_bounds__(128) void prep_kernel(
    const int* __restrict__ m1, const int* __restrict__ m2,
    const int* __restrict__ mu, const float* __restrict__ mult,
    int K, float* __restrict__ Cd) {
    const int t = threadIdx.x;
    for (int i = t; i < CSIZE; i += 128) Cd[i] = 0.f;
    __syncthreads();                       // orders block's global writes
    if (t < K) {
        const int idx = (m1[t] * M_CH + m2[t]) * M_CH + mu[t];
        atomicAdd(&Cd[idx], mult[t]);      // duplicates accumulate
    }
}

__global__ __launch_bounds__(64) void cleb_dense(
    const float* __restrict__ X1, const float* __restrict__ X2,
    const float* __restrict__ Cd, float* __restrict__ out, int P) {
    const int lane = threadIdx.x;
    const size_t base = (size_t)blockIdx.x * 256 + (size_t)lane * 4;

    // 18 independent 16B input loads issued up front
    v2f x1[M_CH][2], x2[M_CH][2];
    #pragma unroll
    for (int m = 0; m < M_CH; ++m) {
        const float4 a = *(const float4*)(X1 + (size_t)m * P + base);
        const float4 b = *(const float4*)(X2 + (size_t)m * P + base);
        x1[m][0] = (v2f){a.x, a.y}; x1[m][1] = (v2f){a.z, a.w};
        x2[m][0] = (v2f){b.x, b.y}; x2[m][1] = (v2f){b.z, b.w};
    }

    v2f acc[M_CH][2];
    #pragma unroll
    for (int m = 0; m < M_CH; ++m) { acc[m][0] = (v2f)0.f; acc[m][1] = (v2f)0.f; }

    #pragma unroll
    for (int p1 = 0; p1 < M_CH; ++p1) {
        #pragma unroll
        for (int p2 = 0; p2 < M_CH; ++p2) {
            const v2f prod0 = x1[p1][0] * x2[p2][0];     // v_pk_mul_f32
            const v2f prod1 = x1[p1][1] * x2[p2][1];
            #pragma unroll
            for (int m = 0; m < M_CH; ++m) {
                // compile-time idx + uniform pointer -> scalar (s_load) fetch
                const float c = Cd[(p1 * M_CH + p2) * M_CH + m];
                const v2f cv = (v2f){c, c};
                acc[m][0] = __builtin_elementwise_fma(cv, prod0, acc[m][0]);
                acc[m][1] = __builtin_elementwise_fma(cv, prod1, acc[m][1]);
            }
        }
    }

    #pragma unroll
    for (int m = 0; m < M_CH; ++m) {
        float4 r;
        r.x = acc[m][0].x; r.y = acc[m][0].y;
        r.z = acc[m][1].x; r.w = acc[m][1].y;
        *(float4*)(out + (size_t)m * P + base) = r;
    }
}

extern "C" void kernel_launch(void* const* d_in, const int* in_sizes, int n_in,
                              void* d_out, int out_size, void* d_ws, size_t ws_size,
                              hipStream_t stream) {
    const float* X1   = (const float*)d_in[0];
    const float* X2   = (const float*)d_in[1];
    const int*   m1   = (const int*)d_in[2];
    const int*   m2   = (const int*)d_in[3];
    const int*   mu   = (const int*)d_in[4];
    const float* mult = (const float*)d_in[5];
    float* out = (float*)d_out;
    float* Cd  = (float*)d_ws;

    const int K = in_sizes[2];                 // 100
    const int P = in_sizes[0] / M_CH;          // 1048576

    prep_kernel<<<1, 128, 0, stream>>>(m1, m2, mu, mult, K, Cd);
    cleb_dense<<<P / 256, 64, 0, stream>>>(X1, X2, Cd, out, P);
}